// Round 11
// baseline (269.279 us; speedup 1.0000x reference)
//
#include <hip/hip_runtime.h>
#include <math.h>

#define E_DIM 1024
#define H_NUM 16
#define HD 64
#define B_NUM 2
#define T_LEN 2048

typedef unsigned short u16;
typedef short bf16x8 __attribute__((ext_vector_type(8)));
typedef float f32x4 __attribute__((ext_vector_type(4)));
typedef unsigned short u16x4 __attribute__((ext_vector_type(4)));
typedef unsigned short u16x8 __attribute__((ext_vector_type(8)));
typedef unsigned int u32x2 __attribute__((ext_vector_type(2)));

#define MFMA16(a, b, c) __builtin_amdgcn_mfma_f32_16x16x32_bf16(a, b, c, 0, 0, 0)

__device__ __forceinline__ u16 f2bf(float f) {
    unsigned u = __float_as_uint(f);
    u += 0x7FFFu + ((u >> 16) & 1u);   // RNE
    return (u16)(u >> 16);
}
__device__ __forceinline__ float bf2f(u16 b) {
    return __uint_as_float(((unsigned)b) << 16);
}
// async global->LDS 16B copy. LDS dest must be wave-uniform base + lane*16.
__device__ __forceinline__ void gl_lds16(const void* g, void* l) {
    __builtin_amdgcn_global_load_lds(
        (const __attribute__((address_space(1))) unsigned int*)g,
        (__attribute__((address_space(3))) unsigned int*)l, 16, 0, 0);
}

// Packed fragment-major layouts (chunk = 64 lanes x 8 u16 = 1KB, lane-contiguous):
//   A/B-frag chunk for 16x16x32: lane = ((kk>>3 & 3)<<4) | (row & 15), pos = kk & 7.
// wtp  [ct(192)][ke(32)]  : ct = col/16 over 3072 cols, ke = e/32
// wop  [ct(64)][ke(32)]
// qp/kp[hb(32)][nt(128)][ks(2)] : nt = t/16, ks = d/32
// vp   [hb(32)][st(32)][ks(2)][dt(4)] : key = st*64+..., d-row = dt*16+...

// ---------------------------------------------------------------------------
// Fused conversion kernel: grid 5376 = 4096 (x) + 768 (Wq/k/v) + 512 (Wo).
// ---------------------------------------------------------------------------
__global__ __launch_bounds__(256) void convert_all_kernel(
    const float* __restrict__ x,
    const float* __restrict__ Wq, const float* __restrict__ Wk, const float* __restrict__ Wv,
    const float* __restrict__ Wo,
    u16* __restrict__ xh, u16* __restrict__ xl,
    u16* __restrict__ wtp_h, u16* __restrict__ wtp_l,
    u16* __restrict__ wop)
{
    const int bid = blockIdx.x;
    const int tid = threadIdx.x;

    if (bid < 4096) {
        int i = (bid * 256 + tid) * 4;
        float4 f = *(const float4*)&x[i];
        float fv[4] = {f.x, f.y, f.z, f.w};
        u16x4 h, l;
        #pragma unroll
        for (int j = 0; j < 4; j++) {
            u16 hi = f2bf(fv[j]);
            h[j] = hi;
            l[j] = f2bf(fv[j] - bf2f(hi));
        }
        *(u16x4*)&xh[i] = h;
        *(u16x4*)&xl[i] = l;
    } else if (bid < 4096 + 768) {
        const int bx = bid - 4096;
        const int m = bx >> 8, h = (bx >> 4) & 15, e0 = (bx & 15) * 64;
        const float* W = (m == 0 ? Wq : (m == 1 ? Wk : Wv));

        __shared__ u16 Th[64][65];   // Th[col][e_local]
        __shared__ u16 Tl[64][65];

        #pragma unroll
        for (int j = 0; j < 16; j++) {
            int idx = j * 256 + tid;
            int e = idx >> 6, i = idx & 63;
            float f = W[((size_t)h * E_DIM + e0 + e) * HD + i];
            u16 hi = f2bf(f);
            Th[i][e] = hi;
            Tl[i][e] = f2bf(f - bf2f(hi));
        }
        __syncthreads();
        #pragma unroll
        for (int rep = 0; rep < 2; rep++) {
            int c = rep * 256 + tid;
            int ct_loc = c >> 7, ke_loc = (c >> 6) & 1, lane = c & 63;
            int col = ct_loc * 16 + (lane & 15);
            int el  = ke_loc * 32 + (lane >> 4) * 8;
            int ct_g = m * 64 + h * 4 + ct_loc;
            int ke_g = (bx & 15) * 2 + ke_loc;
            size_t off = ((size_t)ct_g * 32 + ke_g) * 512 + (size_t)lane * 8;
            *(u16x8*)&wtp_h[off] = *(u16x8*)&Th[col][el];
            *(u16x8*)&wtp_l[off] = *(u16x8*)&Tl[col][el];
        }
    } else {
        int c = (bid - 4096 - 768) * 256 + tid;   // 0..131071
        int lane = c & 63, ke = (c >> 6) & 31, ct = c >> 11;
        int row = ct * 16 + (lane & 15);
        int e   = ke * 32 + (lane >> 4) * 8;
        const float* src = &Wo[(size_t)row * E_DIM + e];
        float4 f0 = *(const float4*)&src[0];
        float4 f1 = *(const float4*)&src[4];
        float fv[8] = {f0.x, f0.y, f0.z, f0.w, f1.x, f1.y, f1.z, f1.w};
        u16x8 hv;
        #pragma unroll
        for (int j = 0; j < 8; j++) hv[j] = f2bf(fv[j]);
        *(u16x8*)&wop[(size_t)c * 8] = hv;
    }
}

// ---------------------------------------------------------------------------
// Fused QKV GEMM, 128x128 tiles, BK=32. q/k: 3-term hi/lo; v: 1-term.
// grid (24, 32) = 768 = 3/CU round-robin (one q, one k, one v block per CU).
// q pre-scaled by log2(e)/sqrt(T) so attention softmax runs in exp2 domain.
// ---------------------------------------------------------------------------
__global__ __launch_bounds__(256, 3) void qkv_mfma_kernel(
    const u16* __restrict__ xh, const u16* __restrict__ xl,
    const u16* __restrict__ wtp_h, const u16* __restrict__ wtp_l,
    u16* __restrict__ qp_h, u16* __restrict__ qp_l,
    u16* __restrict__ kp_h, u16* __restrict__ kp_l,
    u16* __restrict__ vp)
{
    const int bx = blockIdx.x;         // 0..23: col-tile over 3072 packed cols
    const int r0 = blockIdx.y * 128;   // global row (b*T + t)
    const int m  = bx >> 3;            // 0=q 1=k 2=v
    const bool lo = (m != 2);

    __shared__ __align__(16) u16 SM[17408];
    u16* Ah = SM;             // 4096
    u16* Al = SM + 4096;      // 4096
    u16* Bh = SM + 8192;      // 4096
    u16* Bl = SM + 12288;     // 4096

    const int tid = threadIdx.x;
    const int w = tid >> 6, lane = tid & 63;
    const int qd = lane >> 4, n16 = lane & 15;
    const int wr = w >> 1, wc = w & 1;   // rows wr*64..+63, cols wc*64..+63

    f32x4 acc[4][4];
    #pragma unroll
    for (int i = 0; i < 4; i++)
        #pragma unroll
        for (int j = 0; j < 4; j++) acc[i][j] = (f32x4){0.f, 0.f, 0.f, 0.f};

    for (int k0 = 0; k0 < E_DIM; k0 += 32) {
        __syncthreads();
        const int ke = k0 >> 5;
        #pragma unroll
        for (int rep = 0; rep < 2; rep++) {
            int c = rep * 256 + tid;
            int mt = c >> 6;
            int cl = c & 63;
            int cn = cl & 15, cq = cl >> 4;
            size_t aoff = (size_t)(r0 + mt * 16 + cn) * E_DIM + k0 + cq * 8;
            gl_lds16(&xh[aoff], &Ah[c * 8]);
            if (lo) gl_lds16(&xl[aoff], &Al[c * 8]);
        }
        #pragma unroll
        for (int rep = 0; rep < 2; rep++) {
            int c = rep * 256 + tid;
            int ct_loc = c >> 6;
            int cl = c & 63;
            size_t boff = ((size_t)(bx * 8 + ct_loc) * 32 + ke) * 512 + (size_t)cl * 8;
            gl_lds16(&wtp_h[boff], &Bh[c * 8]);
            if (lo) gl_lds16(&wtp_l[boff], &Bl[c * 8]);
        }
        __syncthreads();

        bf16x8 ah[4], al_[4];
        #pragma unroll
        for (int i = 0; i < 4; i++) {
            ah[i] = *(bf16x8*)&Ah[((wr * 4 + i) * 64 + lane) * 8];
            if (lo) al_[i] = *(bf16x8*)&Al[((wr * 4 + i) * 64 + lane) * 8];
        }
        #pragma unroll
        for (int j = 0; j < 4; j++) {
            bf16x8 bh = *(bf16x8*)&Bh[((wc * 4 + j) * 64 + lane) * 8];
            if (lo) {
                bf16x8 bl = *(bf16x8*)&Bl[((wc * 4 + j) * 64 + lane) * 8];
                #pragma unroll
                for (int i = 0; i < 4; i++) {
                    acc[i][j] = MFMA16(ah[i], bh, acc[i][j]);
                    acc[i][j] = MFMA16(al_[i], bh, acc[i][j]);
                    acc[i][j] = MFMA16(ah[i], bl, acc[i][j]);
                }
            } else {
                #pragma unroll
                for (int i = 0; i < 4; i++)
                    acc[i][j] = MFMA16(ah[i], bh, acc[i][j]);
            }
        }
    }

    const int b  = r0 >> 11;
    const int tloc0 = r0 & 2047;

    if (m == 2) {
        const int h0 = (bx & 7) * 2;
        __syncthreads();
        const int VS = 136;
        u16* TR = SM + wc * 8704;
        #pragma unroll
        for (int i = 0; i < 4; i++) {
            int tl = wr * 64 + i * 16 + qd * 4;
            #pragma unroll
            for (int j = 0; j < 4; j++) {
                int d = j * 16 + n16;
                u16x4 pv;
                #pragma unroll
                for (int r = 0; r < 4; r++) pv[r] = f2bf(acc[i][j][r]);
                *(u16x4*)&TR[d * VS + tl] = pv;
            }
        }
        __syncthreads();
        const int st_g0 = tloc0 >> 6;
        #pragma unroll
        for (int rep = 0; rep < 8; rep++) {
            int c = rep * 256 + tid;
            int hh = c >> 10;
            int idx = c & 1023;
            int st_loc = idx >> 9, ks = (idx >> 8) & 1, dt = (idx >> 6) & 3, cl = idx & 63;
            int d  = dt * 16 + (cl & 15);
            int tl = st_loc * 64 + ks * 32 + (cl >> 4) * 8;
            u16x8 v8 = *(u16x8*)&SM[hh * 8704 + d * VS + tl];
            int hbv = (h0 + hh) * 2 + b;
            size_t off = ((((size_t)hbv * 32 + st_g0 + st_loc) * 2 + ks) * 4 + dt) * 512
                       + (size_t)cl * 8;
            *(u16x8*)&vp[off] = v8;
        }
    } else {
        const int h0 = (bx & 7) * 2;
        // q pre-scaled by log2(e)/sqrt(2048): softmax runs in exp2 domain
        const float sc = (m == 0) ? 0.031882937f : 1.0f;
        u16* oh = (m == 0) ? qp_h : kp_h;
        u16* ol = (m == 0) ? qp_l : kp_l;
        const int hb = (h0 + wc) * 2 + b;
        #pragma unroll
        for (int i = 0; i < 4; i++) {
            int nt = (tloc0 >> 4) + wr * 4 + i;
            #pragma unroll
            for (int j = 0; j < 4; j++) {
                int ks = j >> 1;
                int lp = (((j & 1) * 2 + (n16 >> 3)) << 4);
                int pos = n16 & 7;
                size_t cb = (((size_t)hb * 128 + nt) * 2 + ks) * 512;
                #pragma unroll
                for (int r = 0; r < 4; r++) {
                    float f = acc[i][j][r] * sc;
                    u16 hi = f2bf(f);
                    size_t o = cb + (size_t)(lp | (qd * 4 + r)) * 8 + pos;
                    oh[o] = hi;
                    ol[o] = f2bf(f - bf2f(hi));
                }
            }
        }
    }
}

// ---------------------------------------------------------------------------
// Flash attention (transposed), R11: BARRIER-FREE. kp is packed frag-major,
// so the old LDS staging was a pass-through copy — K hi/lo now loads
// directly global->VGPR (lane-contiguous 16B, L1-broadcast across the
// block's waves, L2-resident per XCD via the hb swizzle). LDS holds only
// the wave-private PT buffer; there is NO __syncthreads in this kernel.
// V loaded after K is dead to cap VGPR pressure (3 blocks/CU).
// ---------------------------------------------------------------------------
__global__ __launch_bounds__(256, 3) void attn_kernel(
    const u16* __restrict__ qp_h, const u16* __restrict__ qp_l,
    const u16* __restrict__ kp_h, const u16* __restrict__ kp_l,
    const u16* __restrict__ vp, u16* __restrict__ attb)
{
    const int hb = blockIdx.x;       // 0..31 (= h*2 + b) — XCD = hb%8
    const int h = hb >> 1, b = hb & 1;
    const int t0 = blockIdx.y * 64;

    __shared__ __align__(16) u16 PT[4][16][72];   // 9KB, wave-private

    const int tid  = threadIdx.x;
    const int lane = tid & 63;
    const int w    = tid >> 6;
    const int qd   = lane >> 4;
    const int n16  = lane & 15;

    // Q^T B-frags (scale log2(e)/sqrt(T) folded in upstream)
    bf16x8 bqh[2], bql[2];
    {
        int qt = (t0 >> 4) + w;
        #pragma unroll
        for (int ks = 0; ks < 2; ks++) {
            size_t off = (((size_t)hb * 128 + qt) * 2 + ks) * 512 + (size_t)lane * 8;
            bqh[ks] = *(const bf16x8*)&qp_h[off];
            bql[ks] = *(const bf16x8*)&qp_l[off];
        }
    }

    f32x4 o4[4];
    #pragma unroll
    for (int dt = 0; dt < 4; dt++) o4[dt] = (f32x4){0.f, 0.f, 0.f, 0.f};
    float mr = -1e30f, lr = 0.f;

    for (int st = 0; st < T_LEN / 64; st++) {
        // K(st) hi/lo A-frags direct from packed global (16 x 16B coalesced)
        const size_t kb = ((size_t)hb * 128 + st * 4) * 1024;   // *2*512
        bf16x8 akh[2][4], akl[2][4];
        #pragma unroll
        for (int ks = 0; ks < 2; ks++)
            #pragma unroll
            for (int c = 0; c < 4; c++) {
                size_t o = kb + (size_t)((c * 2 + ks) * 64 + lane) * 8;
                akh[ks][c] = *(const bf16x8*)&kp_h[o];
                akl[ks][c] = *(const bf16x8*)&kp_l[o];
            }

        // S^T = K Q^T, 3-term hi/lo
        f32x4 s[4];
        #pragma unroll
        for (int c = 0; c < 4; c++) s[c] = (f32x4){0.f, 0.f, 0.f, 0.f};
        #pragma unroll
        for (int ks = 0; ks < 2; ks++) {
            #pragma unroll
            for (int c = 0; c < 4; c++) {
                s[c] = MFMA16(akh[ks][c], bqh[ks], s[c]);
                s[c] = MFMA16(akh[ks][c], bql[ks], s[c]);
                s[c] = MFMA16(akl[ks][c], bqh[ks], s[c]);
            }
        }

        // online softmax in exp2 domain (query = lane column n16)
        float tmax = s[0][0];
        #pragma unroll
        for (int c = 0; c < 4; c++)
            #pragma unroll
            for (int r = 0; r < 4; r++) tmax = fmaxf(tmax, s[c][r]);
        tmax = fmaxf(tmax, __shfl_xor(tmax, 16));
        tmax = fmaxf(tmax, __shfl_xor(tmax, 32));
        float nm = fmaxf(mr, tmax);
        float al = __builtin_amdgcn_exp2f(mr - nm);   // == 1.0 iff max unchanged
        mr = nm;

        float psum = 0.f;
        #pragma unroll
        for (int c = 0; c < 4; c++) {
            float p0 = __builtin_amdgcn_exp2f(s[c][0] - nm);
            float p1 = __builtin_amdgcn_exp2f(s[c][1] - nm);
            float p2 = __builtin_amdgcn_exp2f(s[c][2] - nm);
            float p3 = __builtin_amdgcn_exp2f(s[c][3] - nm);
            psum += (p0 + p1) + (p2 + p3);
            u32x2 pk;   // truncating bf16 pack (P in [0,1], bias cancels)
            pk[0] = (__float_as_uint(p0) >> 16) | (__float_as_uint(p1) & 0xFFFF0000u);
            pk[1] = (__float_as_uint(p2) >> 16) | (__float_as_uint(p3) & 0xFFFF0000u);
            *(u32x2*)&PT[w][n16][c * 16 + qd * 4] = pk;
        }
        if (__any(al != 1.0f)) {
            lr *= al;
            #pragma unroll
            for (int dt = 0; dt < 4; dt++)
                #pragma unroll
                for (int r = 0; r < 4; r++) o4[dt][r] *= al;
        }
        lr += psum;

        // V(st) direct global->VGPR (K regs dead by now)
        bf16x8 av[4][2];
        #pragma unroll
        for (int ks = 0; ks < 2; ks++)
            #pragma unroll
            for (int dt = 0; dt < 4; dt++) {
                size_t off = ((((size_t)hb * 32 + st) * 2 + ks) * 4 + dt) * 512
                           + (size_t)lane * 8;
                av[dt][ks] = *(const bf16x8*)&vp[off];
            }

        // O^T += V^T P^T  (PT wave-private: same-wave LDS ordering suffices)
        #pragma unroll
        for (int ks = 0; ks < 2; ks++) {
            bf16x8 bp = *(bf16x8*)&PT[w][n16][ks * 32 + qd * 8];
            #pragma unroll
            for (int dt = 0; dt < 4; dt++)
                o4[dt] = MFMA16(av[dt][ks], bp, o4[dt]);
        }
    }

    lr += __shfl_xor(lr, 16);
    lr += __shfl_xor(lr, 32);
    float inv = 1.f / lr;
    int row = t0 + w * 16 + n16;
    #pragma unroll
    for (int dt = 0; dt < 4; dt++) {
        u16x4 ov;
        #pragma unroll
        for (int r = 0; r < 4; r++) ov[r] = f2bf(o4[dt][r] * inv);
        *(u16x4*)&attb[(size_t)(b * T_LEN + row) * E_DIM + h * HD + dt * 16 + qd * 4] = ov;
    }
}

// ---------------------------------------------------------------------------
// Output projection: out(4096x1024 fp32) = attb(bf16) @ Wo^T.
// 128(M) x 64(N), BK=64, grid (16,32)=512 blocks. A staged; B direct packed.
// ---------------------------------------------------------------------------
__global__ __launch_bounds__(256) void outproj_mfma_kernel(
    const u16* __restrict__ attb, const u16* __restrict__ wop,
    float* __restrict__ out)
{
    const int c0 = blockIdx.x * 64;
    const int r0 = blockIdx.y * 128;

    __shared__ __align__(16) u16 As[8192];   // 16KB

    const int tid = threadIdx.x;
    const int w = tid >> 6, lane = tid & 63;
    const int qd = lane >> 4, n16 = lane & 15;
    const int wr = w >> 1, wc = w & 1;

    f32x4 acc[4][2];
    #pragma unroll
    for (int i = 0; i < 4; i++)
        #pragma unroll
        for (int j = 0; j < 2; j++) acc[i][j] = (f32x4){0.f, 0.f, 0.f, 0.f};

    for (int k0 = 0; k0 < E_DIM; k0 += 64) {
        __syncthreads();
        #pragma unroll
        for (int rep = 0; rep < 4; rep++) {
            int c = rep * 256 + tid;
            int mt = c >> 7, ks = (c >> 6) & 1;
            int cl = c & 63;
            int cn = cl & 15, cq = cl >> 4;
            gl_lds16(&attb[(size_t)(r0 + mt * 16 + cn) * E_DIM + k0 + ks * 32 + cq * 8],
                     &As[c * 8]);
        }
        bf16x8 bb[2][2];
        #pragma unroll
        for (int j = 0; j < 2; j++) {
            int ct = (c0 >> 4) + wc * 2 + j;
            #pragma unroll
            for (int ks = 0; ks < 2; ks++) {
                int ke = (k0 >> 5) + ks;
                bb[j][ks] = *(const bf16x8*)&wop[((size_t)ct * 32 + ke) * 512 + (size_t)lane * 8];
            }
        }
        __syncthreads();

        #pragma unroll
        for (int ks = 0; ks < 2; ks++) {
            bf16x8 a[4];
            #pragma unroll
            for (int i = 0; i < 4; i++)
                a[i] = *(bf16x8*)&As[(((wr * 4 + i) * 2 + ks) * 64 + lane) * 8];
            #pragma unroll
            for (int j = 0; j < 2; j++)
                #pragma unroll
                for (int i = 0; i < 4; i++)
                    acc[i][j] = MFMA16(a[i], bb[j][ks], acc[i][j]);
        }
    }

    #pragma unroll
    for (int i = 0; i < 4; i++) {
        #pragma unroll
        for (int r = 0; r < 4; r++) {
            int row = r0 + wr * 64 + i * 16 + qd * 4 + r;
            #pragma unroll
            for (int j = 0; j < 2; j++) {
                int col = c0 + wc * 32 + j * 16 + n16;
                out[(size_t)row * E_DIM + col] = acc[i][j][r];
            }
        }
    }
}

extern "C" void kernel_launch(void* const* d_in, const int* in_sizes, int n_in,
                              void* d_out, int out_size, void* d_ws, size_t ws_size,
                              hipStream_t stream)
{
    const float* x  = (const float*)d_in[0];
    const float* Wq = (const float*)d_in[1];
    const float* Wk = (const float*)d_in[2];
    const float* Wv = (const float*)d_in[3];
    const float* Wo = (const float*)d_in[4];
    float* out = (float*)d_out;

    const size_t NX = (size_t)4096 * 1024;
    const size_t NW = (size_t)3072 * 1024;
    const size_t NO = (size_t)1024 * 1024;
    const size_t NQ = (size_t)H_NUM * B_NUM * T_LEN * HD;

    u16* xh   = (u16*)d_ws;
    u16* xl   = xh + NX;
    u16* wtph = xl + NX;
    u16* wtpl = wtph + NW;
    u16* wop  = wtpl + NW;
    u16* qph  = wop + NO;
    u16* qpl  = qph + NQ;
    u16* kph  = qpl + NQ;
    u16* kpl  = kph + NQ;
    u16* vp   = kpl + NQ;
    u16* attb = xh;   // alias: xh dead after qkv_mfma

    convert_all_kernel<<<4096 + 768 + 512, 256, 0, stream>>>(
        x, Wq, Wk, Wv, Wo, xh, xl, wtph, wtpl, wop);

    dim3 g1(24, 32);
    qkv_mfma_kernel<<<g1, 256, 0, stream>>>(xh, xl, wtph, wtpl, qph, qpl, kph, kpl, vp);

    dim3 g2(H_NUM * B_NUM, T_LEN / 64);   // x = hb for XCD-L2 locality
    attn_kernel<<<g2, 256, 0, stream>>>(qph, qpl, kph, kpl, vp, attb);

    dim3 g3(E_DIM / 64, 4096 / 128);
    outproj_mfma_kernel<<<g3, 256, 0, stream>>>(attb, wop, out);
}